// Round 13
// baseline (82.681 us; speedup 1.0000x reference)
//
#include <hip/hip_runtime.h>
#include <math.h>

#define BB 4
#define NN 4096
#define MM 512
#define NPTS_TOT (BB * NN)     // 16384 points
#define NTRI_TOT (BB * MM)     // 2048 triangles
#define NSPLIT 16              // m-splits: 32 triangles each
#define MSEG (MM / NSPLIT)     // 32

// reference _safe_div guard + hw rcp (~1 ulp) -- relative-class error, argmin-safe (R4-R12 validated)
__device__ __forceinline__ float safercp(float y) {
    float yy = (fabsf(y) < 1e-12f) ? 1.0f : y;
    return __builtin_amdgcn_rcpf(yy);
}

// exact IEEE version for phase-2 (matches reference bit-order, validated R1/R3/R6-R12)
__device__ __forceinline__ float safediv(float x, float y) {
    float yy = (fabsf(y) < 1e-12f) ? 1.0f : y;
    return x / yy;
}

__device__ __forceinline__ float clip01s(float x) {
    return fminf(fmaxf(x, 0.0f), 1.0f);   // v_med3_f32
}

// Phase 2: exact reference-ordered Ericson for ONE pair (R1-validated numerics).
__device__ void exact_pair(float px, float py, float pz,
                           float ax, float ay, float az,
                           float bx, float by, float bz,
                           float cx, float cy, float cz,
                           float* dist2_out, int* reg_out) {
#pragma clang fp contract(off)
    const float abx = bx-ax, aby = by-ay, abz = bz-az;
    const float acx = cx-ax, acy = cy-ay, acz = cz-az;
    const float cbx = cx-bx, cby = cy-by, cbz = cz-bz;
    const float apx = px-ax, apy = py-ay, apz = pz-az;
    const float bpx = px-bx, bpy = py-by, bpz = pz-bz;
    const float cpx = px-cx, cpy = py-cy, cpz = pz-cz;

    const float d1 = abx*apx + aby*apy + abz*apz;
    const float d2 = acx*apx + acy*apy + acz*apz;
    const float d3 = abx*bpx + aby*bpy + abz*bpz;
    const float d4 = acx*bpx + acy*bpy + acz*bpz;
    const float d5 = abx*cpx + aby*cpy + abz*cpz;
    const float d6 = acx*cpx + acy*cpy + acz*cpz;

    const float vc = d1*d4 - d3*d2;
    const float vb = d5*d2 - d1*d6;
    const float va = d3*d6 - d5*d4;

    const float v_ab = clip01s(safediv(d1, d1 - d3));
    const float v_ac = clip01s(safediv(d2, d2 - d6));
    const float t43 = d4 - d3;
    const float t56 = d5 - d6;
    const float v_bc = clip01s(safediv(t43, t43 + t56));
    const float denom = va + vb + vc;
    const float v_f = safediv(vb, denom);
    const float w_f = safediv(vc, denom);

    float qx = ax + v_f*abx + w_f*acx;
    float qy = ay + v_f*aby + w_f*acy;
    float qz = az + v_f*abz + w_f*acz;
    int reg = 6;
    const bool c_bc = (va <= 0.0f) && (t43 >= 0.0f) && (t56 >= 0.0f);
    if (c_bc) { qx = bx + v_bc*cbx; qy = by + v_bc*cby; qz = bz + v_bc*cbz; reg = 5; }
    const bool c_ac = (vb <= 0.0f) && (d2 >= 0.0f) && (d6 <= 0.0f);
    if (c_ac) { qx = ax + v_ac*acx; qy = ay + v_ac*acy; qz = az + v_ac*acz; reg = 4; }
    const bool c_c = (d6 >= 0.0f) && (d5 <= d6);
    if (c_c) { qx = cx; qy = cy; qz = cz; reg = 2; }
    const bool c_ab = (vc <= 0.0f) && (d1 >= 0.0f) && (d3 <= 0.0f);
    if (c_ab) { qx = ax + v_ab*abx; qy = ay + v_ab*aby; qz = az + v_ab*abz; reg = 3; }
    const bool c_b = (d3 >= 0.0f) && (d4 <= d3);
    if (c_b) { qx = bx; qy = by; qz = bz; reg = 1; }
    const bool c_a = (d1 <= 0.0f) && (d2 <= 0.0f);
    if (c_a) { qx = ax; qy = ay; qz = az; reg = 0; }

    const float dx = px - qx;
    const float dy = py - qy;
    const float dz = pz - qz;
    *dist2_out = dx*dx + dy*dy + dz*dz;
    *reg_out = reg;
}

// ---- kernel 0: per-triangle constants -> d_ws (24 floats each) ----
// Identical formulas/order to R12's in-kernel precompute (bit-identical phase-1).
__global__ __launch_bounds__(256) void tridist_setup(
    const float* __restrict__ tri1, const float* __restrict__ tri2,
    const float* __restrict__ tri3, float* __restrict__ pre)
{
    const int g = blockIdx.x * 256 + threadIdx.x;    // [0, 2048)
    const float* g1 = tri1 + (size_t)g * 3;
    const float* g2 = tri2 + (size_t)g * 3;
    const float* g3 = tri3 + (size_t)g * 3;
    const float ax = g1[0], ay = g1[1], az = g1[2];
    const float bx = g2[0], by = g2[1], bz = g2[2];
    const float cx = g3[0], cy = g3[1], cz = g3[2];
    const float abx = bx-ax, aby = by-ay, abz = bz-az;
    const float acx = cx-ax, acy = cy-ay, acz = cz-az;
    const float cbx = cx-bx, cby = cy-by, cbz = cz-bz;
    const float naba  = -fmaf(abz, az, fmaf(aby, ay, abx*ax));
    const float naca  = -fmaf(acz, az, fmaf(acy, ay, acx*ax));
    const float ab2   = fmaf(abz, abz, fmaf(aby, aby, abx*abx));
    const float ac2   = fmaf(acz, acz, fmaf(acy, acy, acx*acx));
    const float cb2   = fmaf(cbz, cbz, fmaf(cby, cby, cbx*cbx));
    const float abac  = fmaf(abz, acz, fmaf(aby, acy, abx*acx));
    const float nrx = fmaf(aby, acz, -(abz*acy));
    const float nry = fmaf(abz, acx, -(abx*acz));
    const float nrz = fmaf(abx, acy, -(aby*acx));
    const float n2  = fmaf(nrz, nrz, fmaf(nry, nry, nrx*nrx));
    const float rn  = __builtin_amdgcn_rsqf(fmaxf(n2, 1e-30f));
    const float nx = nrx*rn, ny = nry*rn, nz = nrz*rn;
    const float nna = -fmaf(nz, az, fmaf(ny, ay, nx*ax));

    float4* p4 = (float4*)(pre + (size_t)g * 24);
    p4[0] = make_float4(abx, aby, abz, naba);
    p4[1] = make_float4(acx, acy, acz, naca);
    p4[2] = make_float4(nx, ny, nz, nna);
    p4[3] = make_float4(-ab2, -abac, -ac2, safercp(ab2));
    p4[4] = make_float4(safercp(ac2), safercp(cb2), ax, ay);
    p4[5] = make_float4(az, cbx, cby, cbz);
}

// ---- kernel 1: main. lane = point, uniform s_load triangle constants. ----
// No LDS, no shuffles, no cross-lane ops in the hot loop: pure VALU.
__global__ __launch_bounds__(256) void tridist_p1(
    const float* __restrict__ xyz1, const float* __restrict__ pre,
    float* __restrict__ wd, int* __restrict__ wj)
{
    const int t    = threadIdx.x;
    const int lane = t & 63;
    // wave id made explicitly wave-uniform so triangle addressing scalarizes
    const int w    = __builtin_amdgcn_readfirstlane(t >> 6);   // [0,4)
    const int pg   = blockIdx.x >> 2;        // point-group [0,256): 64 points
    const int spl  = (blockIdx.x & 3) * 4 + w;                 // split [0,16)
    const int b    = pg >> 6;                // 64 point-groups per batch
    const int point = pg * 64 + lane;        // global point id [0,16384)

    const float px = xyz1[point*3 + 0];
    const float py = xyz1[point*3 + 1];
    const float pz = xyz1[point*3 + 2];

    const int jlocal0 = spl * MSEG;          // triangle base within batch
    const float* tp0 = pre + ((size_t)b * MM + jlocal0) * 24;

    float bestd = INFINITY;
    int   bestj = 0;

#pragma unroll 4
    for (int i = 0; i < MSEG; ++i) {
        const float* tp = tp0 + (size_t)i * 24;   // uniform -> s_load
        const float abx = tp[0],  aby = tp[1],  abz = tp[2],  naba = tp[3];
        const float acx = tp[4],  acy = tp[5],  acz = tp[6],  naca = tp[7];
        const float nx  = tp[8],  ny  = tp[9],  nz  = tp[10], nna  = tp[11];
        const float nab2 = tp[12], nabac = tp[13], nac2 = tp[14], rab2 = tp[15];
        const float rac2 = tp[16], rcb2 = tp[17], ax = tp[18], ay = tp[19];
        const float az  = tp[20], cbx = tp[21], cby = tp[22], cbz = tp[23];

        const float d1 = fmaf(abz, pz, fmaf(aby, py, fmaf(abx, px, naba)));
        const float d2 = fmaf(acz, pz, fmaf(acy, py, fmaf(acx, px, naca)));
        const float h  = fmaf(nz,  pz, fmaf(ny,  py, fmaf(nx,  px, nna)));
        const float d3 = d1 + nab2;
        const float d4 = d2 + nabac;
        const float d5 = d1 + nabac;
        const float d6 = d2 + nac2;

        const float vc = fmaf(d1, d4, -(d3*d2));
        const float vb = fmaf(d5, d2, -(d1*d6));
        const float va = fmaf(d3, d6, -(d5*d4));
        const float t43 = d4 - d3;

        const float uab = clip01s(d1 * rab2);
        const float uac = clip01s(d2 * rac2);
        const float ubc = clip01s(t43 * rcb2);

        const float apx = px - ax, apy = py - ay, apz = pz - az;
        const float bpx = apx - abx, bpy = apy - aby, bpz = apz - abz;

        float ex = fmaf(-uab, abx, apx), ey = fmaf(-uab, aby, apy), ez = fmaf(-uab, abz, apz);
        const float dAB = fmaf(ez, ez, fmaf(ey, ey, ex*ex));
        ex = fmaf(-uac, acx, apx); ey = fmaf(-uac, acy, apy); ez = fmaf(-uac, acz, apz);
        const float dAC = fmaf(ez, ez, fmaf(ey, ey, ex*ex));
        ex = fmaf(-ubc, cbx, bpx); ey = fmaf(-ubc, cby, bpy); ez = fmaf(-ubc, cbz, bpz);
        const float dBC = fmaf(ez, ez, fmaf(ey, ey, ex*ex));
        const float dF = h * h;

        const float mv   = fminf(fminf(va, vb), vc);          // v_min3
        const float dseg = fminf(fminf(dAB, dAC), dBC);       // v_min3
        const float dd   = (mv >= 0.0f) ? dF : dseg;

        // strict < with ascending j: np.argmin first-occurrence
        if (dd < bestd) { bestd = dd; bestj = jlocal0 + i; }
    }

    wd[(size_t)spl * NPTS_TOT + point] = bestd;
    wj[(size_t)spl * NPTS_TOT + point] = bestj;
}

// ---- kernel 2: merge 16 split-partials + exact phase-2 + output ----
__global__ __launch_bounds__(256) void tridist_p2(
    const float* __restrict__ xyz1, const float* __restrict__ tri1,
    const float* __restrict__ tri2, const float* __restrict__ tri3,
    const float* __restrict__ wd, const int* __restrict__ wj,
    float* __restrict__ out)
{
    const int gidx = blockIdx.x * 256 + threadIdx.x;   // [0, 16384)
    float bd = INFINITY; int bj = 0;
    for (int s = 0; s < NSPLIT; ++s) {       // ascending s -> ascending j
        const float dk = wd[(size_t)s * NPTS_TOT + gidx];
        const int   jk = wj[(size_t)s * NPTS_TOT + gidx];
        if (dk < bd) { bd = dk; bj = jk; }   // strict < keeps first occurrence
    }
    const int b = gidx >> 12;                // 4096 points per batch
    const float* g1 = tri1 + ((size_t)b * MM + bj) * 3;
    const float* g2 = tri2 + ((size_t)b * MM + bj) * 3;
    const float* g3 = tri3 + ((size_t)b * MM + bj) * 3;
    float dist2; int reg;
    exact_pair(xyz1[gidx*3+0], xyz1[gidx*3+1], xyz1[gidx*3+2],
               g1[0], g1[1], g1[2],
               g2[0], g2[1], g2[2],
               g3[0], g3[1], g3[2],
               &dist2, &reg);
    out[gidx]               = dist2;
    out[NPTS_TOT + gidx]    = (float)reg;
    out[2*NPTS_TOT + gidx]  = (float)bj;
}

extern "C" void kernel_launch(void* const* d_in, const int* in_sizes, int n_in,
                              void* d_out, int out_size, void* d_ws, size_t ws_size,
                              hipStream_t stream) {
    const float* xyz1 = (const float*)d_in[0];
    const float* tri1 = (const float*)d_in[1];
    const float* tri2 = (const float*)d_in[2];
    const float* tri3 = (const float*)d_in[3];
    float* out = (float*)d_out;

    float* pre = (float*)d_ws;                                   // 2048*24 floats
    float* wd  = pre + (size_t)NTRI_TOT * 24;                    // 16*16384 floats
    int*   wj  = (int*)(wd + (size_t)NSPLIT * NPTS_TOT);         // 16*16384 ints

    tridist_setup<<<NTRI_TOT / 256, 256, 0, stream>>>(tri1, tri2, tri3, pre);

    dim3 grid1((NPTS_TOT / 64) * 4);  // 1024 blocks x 256 thr (4 waves = 4 splits)
    tridist_p1<<<grid1, 256, 0, stream>>>(xyz1, pre, wd, wj);

    tridist_p2<<<NPTS_TOT / 256, 256, 0, stream>>>(xyz1, tri1, tri2, tri3, wd, wj, out);
}